// Round 1
// baseline (191.178 us; speedup 1.0000x reference)
//
#include <hip/hip_runtime.h>
#include <hip/hip_bf16.h>
#include <math.h>

#define Hd   1024
#define Bsz  4096
#define Kc   3072      // concatenated K (3 x 1024)
#define Mrows 4096     // gate rows (4H), row 4096 handled separately

typedef unsigned short u16;
typedef __attribute__((ext_vector_type(8))) u16 u16x8;
typedef __attribute__((ext_vector_type(2))) u16 u16x2;
typedef __attribute__((ext_vector_type(4))) float f32x4;
typedef __attribute__((ext_vector_type(8))) short bf16x8;

__device__ inline u16 f2bf(float f) {
    __hip_bfloat16 h = __float2bfloat16(f);
    return *reinterpret_cast<u16*>(&h);
}

__device__ inline float sigm(float x) { return 1.0f / (1.0f + __expf(-x)); }

__device__ inline void gload16(const void* g, const void* s) {
    __builtin_amdgcn_global_load_lds(
        (const __attribute__((address_space(1))) void*)g,
        (__attribute__((address_space(3))) void*)s, 16, 0, 0);
}

// ---------------------------------------------------------------------------
// prep_A: A_cat bf16 [4096][3072], row m' = 4*r + gate  <-  src row gate*1024+r
//         k' < 1024: W01 | k' < 2048: U21 | else: U11
// ---------------------------------------------------------------------------
__global__ __launch_bounds__(256) void prep_A(const float* __restrict__ U11,
                                              const float* __restrict__ U21,
                                              const float* __restrict__ W01,
                                              u16* __restrict__ Ab) {
    int t = blockIdx.x * 256 + threadIdx.x;       // 4096*384 threads, 8 elems each
    int row = t / 384;
    int kc = (t - row * 384) * 8;
    int r = row >> 2, gate = row & 3;
    int sel = kc >> 10;
    int k = kc & 1023;
    const float* src = (sel == 0) ? W01 : ((sel == 1) ? U21 : U11);
    const float4* p = reinterpret_cast<const float4*>(src + (size_t)(gate * Hd + r) * Hd + k);
    float4 v0 = p[0], v1 = p[1];
    u16x8 o;
    o[0] = f2bf(v0.x); o[1] = f2bf(v0.y); o[2] = f2bf(v0.z); o[3] = f2bf(v0.w);
    o[4] = f2bf(v1.x); o[5] = f2bf(v1.y); o[6] = f2bf(v1.z); o[7] = f2bf(v1.w);
    *reinterpret_cast<u16x8*>(Ab + (size_t)row * Kc + kc) = o;
}

// ---------------------------------------------------------------------------
// prep_B: B_catT bf16 [4096(n)][3072(k')]  (transpose + per-column z gating)
//   k'<1024: h_bottom | k'<2048: z*h_top | else: z_bottom*h
// ---------------------------------------------------------------------------
__global__ __launch_bounds__(256) void prep_B(const float* __restrict__ hb,
                                              const float* __restrict__ ht,
                                              const float* __restrict__ hh,
                                              const float* __restrict__ z,
                                              const float* __restrict__ zb,
                                              u16* __restrict__ Bb) {
    __shared__ float tile[64][33];
    int n0 = blockIdx.x * 32;
    int kg0 = blockIdx.y * 64;
    int sel = kg0 >> 10;
    int k0 = kg0 & 1023;
    const float* src = (sel == 0) ? hb : ((sel == 1) ? ht : hh);
    int t = threadIdx.x, tx = t & 31, ty = t >> 5;
#pragma unroll
    for (int j = 0; j < 8; ++j) {
        int kk = ty * 8 + j;
        tile[kk][tx] = src[(size_t)(k0 + kk) * Bsz + n0 + tx];
    }
    __syncthreads();
    int kp = t & 31, ny = t >> 5;
#pragma unroll
    for (int j = 0; j < 4; ++j) {
        int nl = ny * 4 + j;
        int n = n0 + nl;
        float s = (sel == 0) ? 1.0f : ((sel == 1) ? z[n] : zb[n]);
        u16x2 o;
        o[0] = f2bf(tile[kp * 2][nl] * s);
        o[1] = f2bf(tile[kp * 2 + 1][nl] * s);
        *reinterpret_cast<u16x2*>(Bb + (size_t)n * Kc + kg0 + kp * 2) = o;
    }
}

// ---------------------------------------------------------------------------
// zrow: f32 row 4096 of f_s -> z_new = (s > 0) ? 1 : 0   (straight-through step)
// ---------------------------------------------------------------------------
__global__ __launch_bounds__(256) void zrow(const float* __restrict__ hb,
                                            const float* __restrict__ ht,
                                            const float* __restrict__ hh,
                                            const float* __restrict__ z,
                                            const float* __restrict__ zb,
                                            const float* __restrict__ U11,
                                            const float* __restrict__ U21,
                                            const float* __restrict__ W01,
                                            const float* __restrict__ bias,
                                            float* __restrict__ out) {
    __shared__ float wrow0[1024], wrow1[1024], wrow2[1024];
    __shared__ float red[8][32];
    int t = threadIdx.x;
    for (int i = t; i < 1024; i += 256) {
        wrow0[i] = W01[(size_t)4096 * 1024 + i];
        wrow1[i] = U21[(size_t)4096 * 1024 + i];
        wrow2[i] = U11[(size_t)4096 * 1024 + i];
    }
    __syncthreads();
    int col = t & 31, sl = t >> 5;                 // 8 k-slices of 128
    int n = blockIdx.x * 32 + col;
    float p0 = 0.f, p1 = 0.f, p2 = 0.f;
    int kend = sl * 128 + 128;
    for (int k = sl * 128; k < kend; ++k) {
        p0 += wrow0[k] * hb[(size_t)k * Bsz + n];
        p1 += wrow1[k] * ht[(size_t)k * Bsz + n];
        p2 += wrow2[k] * hh[(size_t)k * Bsz + n];
    }
    red[sl][col] = p0 + z[n] * p1 + zb[n] * p2;
    __syncthreads();
    if (sl == 0) {
        float s = bias[4096];
#pragma unroll
        for (int q = 0; q < 8; ++q) s += red[q][col];
        float zh = (s + 1.0f) * 0.5f;              // A = 1.0 hard sigmoid
        zh = fminf(fmaxf(zh, 0.0f), 1.0f);
        out[(size_t)2 * Hd * Bsz + n] = (zh > 0.5f) ? 1.0f : 0.0f;
    }
}

// ---------------------------------------------------------------------------
// gemm_fused: C = A_cat(4096x3072) * B_catT^T (N=4096), fused LSTM epilogue.
// 128x128 tile, BK=32, 4 waves, 16x16x32 bf16 MFMA, global_load_lds width 16.
// Each lane's 4 acc regs = f,i,o,g of one hidden unit r for one column n.
// ---------------------------------------------------------------------------
__global__ __launch_bounds__(256) void gemm_fused(
    const u16* __restrict__ A, const u16* __restrict__ Bm,
    const float* __restrict__ c_in, const float* __restrict__ h_in,
    const float* __restrict__ z, const float* __restrict__ zb,
    const float* __restrict__ bias, float* __restrict__ out) {
    __shared__ __align__(16) u16 As[128 * 32];
    __shared__ __align__(16) u16 Bs[128 * 32];
    const int t = threadIdx.x;
    const int w = t >> 6, l = t & 63;
    const int bm = blockIdx.x, bn = blockIdx.y;
    const int wr = w >> 1, wc = w & 1;

    f32x4 acc[4][4];
#pragma unroll
    for (int i = 0; i < 4; ++i)
#pragma unroll
        for (int j = 0; j < 4; ++j) acc[i][j] = (f32x4){0.f, 0.f, 0.f, 0.f};

    // staging: wave w loads rows [w*32, w*32+32) of both tiles (2 issues each)
    const int srow = w * 32 + (l >> 2);
    const int skoff = (l & 3) * 8;
    const u16* ga = A + (size_t)(bm * 128 + srow) * Kc + skoff;
    const u16* gb = Bm + (size_t)(bn * 128 + srow) * Kc + skoff;
    u16* lA = As + w * 1024;    // 16 rows * 32 k * (q=0/1 -> +512)
    u16* lB = Bs + w * 1024;

    const int frow = (l & 15);
    const int fk = (l >> 4) * 8;
    const u16* rA = As + (size_t)(wr * 64 + frow) * 32 + fk;
    const u16* rB = Bs + (size_t)(wc * 64 + frow) * 32 + fk;

    for (int kt = 0; kt < Kc; kt += 32) {
        gload16(ga + kt, lA);
        gload16(ga + kt + (size_t)16 * Kc, lA + 512);
        gload16(gb + kt, lB);
        gload16(gb + kt + (size_t)16 * Kc, lB + 512);
        __syncthreads();   // drains vmcnt -> LDS tile ready
        bf16x8 af[4], bfr[4];
#pragma unroll
        for (int mi = 0; mi < 4; ++mi)
            af[mi] = *reinterpret_cast<const bf16x8*>(rA + mi * 16 * 32);
#pragma unroll
        for (int ni = 0; ni < 4; ++ni)
            bfr[ni] = *reinterpret_cast<const bf16x8*>(rB + ni * 16 * 32);
#pragma unroll
        for (int mi = 0; mi < 4; ++mi)
#pragma unroll
            for (int ni = 0; ni < 4; ++ni)
                acc[mi][ni] = __builtin_amdgcn_mfma_f32_16x16x32_bf16(
                    af[mi], bfr[ni], acc[mi][ni], 0, 0, 0);
        __syncthreads();   // all waves done reading before next overwrite
    }

    // fused LSTM epilogue: regs 0..3 = f,i,o,g pre-activations of unit r, col n
    const int r0 = bm * 32 + wr * 16;
    const int n0 = bn * 128 + wc * 64;
#pragma unroll
    for (int mi = 0; mi < 4; ++mi) {
        const int r = r0 + mi * 4 + (l >> 4);
        const float b0 = bias[r], b1 = bias[Hd + r], b2 = bias[2 * Hd + r], b3 = bias[3 * Hd + r];
        const float* crow = c_in + (size_t)r * Bsz;
        const float* hrow = h_in + (size_t)r * Bsz;
#pragma unroll
        for (int ni = 0; ni < 4; ++ni) {
            const int n = n0 + ni * 16 + (l & 15);
            f32x4 a = acc[mi][ni];
            float zc = z[n], zbv = zb[n];
            float co = crow[n], ho = hrow[n];
            float fg = sigm(a[0] + b0);
            float ig = sigm(a[1] + b1);
            float og = sigm(a[2] + b2);
            float gg = tanhf(a[3] + b3);
            float i_g = ig * gg;
            float nz = 1.0f - zc, nzb = 1.0f - zbv;
            float cn = zc * i_g + nz * nzb * co + nz * zbv * (fg * co + i_g);
            float tc = tanhf(cn);
            float hn = zc * og * tc + nz * nzb * ho + nz * zbv * og * tc;
            out[(size_t)r * Bsz + n] = hn;
            out[(size_t)Hd * Bsz + (size_t)r * Bsz + n] = cn;
        }
    }
}

extern "C" void kernel_launch(void* const* d_in, const int* in_sizes, int n_in,
                              void* d_out, int out_size, void* d_ws, size_t ws_size,
                              hipStream_t stream) {
    (void)in_sizes; (void)n_in; (void)out_size; (void)ws_size;
    const float* c    = (const float*)d_in[0];
    const float* hb   = (const float*)d_in[1];
    const float* h    = (const float*)d_in[2];
    const float* ht   = (const float*)d_in[3];
    const float* z    = (const float*)d_in[4];
    const float* zb   = (const float*)d_in[5];
    const float* U11  = (const float*)d_in[6];
    const float* U21  = (const float*)d_in[7];
    const float* W01  = (const float*)d_in[8];
    const float* bias = (const float*)d_in[9];
    float* out = (float*)d_out;

    u16* Ab = (u16*)d_ws;                          // 4096*3072*2 B = 25.2 MB
    u16* Bb = Ab + (size_t)Mrows * Kc;             // another 25.2 MB

    prep_A<<<6144, 256, 0, stream>>>(U11, U21, W01, Ab);
    prep_B<<<dim3(128, 48), 256, 0, stream>>>(hb, ht, h, z, zb, Bb);
    zrow<<<128, 256, 0, stream>>>(hb, ht, h, z, zb, U11, U21, W01, bias, out);
    gemm_fused<<<dim3(32, 32), 256, 0, stream>>>(Ab, Bb, c, h, z, zb, bias, out);
}

// Round 2
// 138.615 us; speedup vs baseline: 1.3792x; 1.3792x over previous
//
#include <hip/hip_runtime.h>
#include <hip/hip_bf16.h>
#include <math.h>

#define Hd   1024
#define Bsz  4096
#define Kc   3072      // concatenated K (3 x 1024)
#define NT   48        // K-tiles of 64

typedef unsigned short u16;
typedef __attribute__((ext_vector_type(8))) u16 u16x8;
typedef __attribute__((ext_vector_type(2))) u16 u16x2;
typedef __attribute__((ext_vector_type(4))) float f32x4;
typedef __attribute__((ext_vector_type(8))) short bf16x8;

template<bool V> struct BoolC { static constexpr bool value = V; };

__device__ inline u16 f2bf(float f) {
    __hip_bfloat16 h = __float2bfloat16(f);
    return *reinterpret_cast<u16*>(&h);
}

__device__ inline float sigm(float x) { return 1.0f / (1.0f + __expf(-x)); }

__device__ inline void gload16(const void* g, const void* s) {
    __builtin_amdgcn_global_load_lds(
        (const __attribute__((address_space(1))) void*)g,
        (__attribute__((address_space(3))) void*)s, 16, 0, 0);
}

#define BAR()   __builtin_amdgcn_s_barrier()
#define LGKM0() asm volatile("s_waitcnt lgkmcnt(0)" ::: "memory")
#define VMW(n)  asm volatile("s_waitcnt vmcnt(" #n ")" ::: "memory")

// ---------------------------------------------------------------------------
// prep_A: A_cat bf16 [4096][3072], row m' = 4*r + gate  <-  src row gate*1024+r
// ---------------------------------------------------------------------------
__global__ __launch_bounds__(256) void prep_A(const float* __restrict__ U11,
                                              const float* __restrict__ U21,
                                              const float* __restrict__ W01,
                                              u16* __restrict__ Ab) {
    int t = blockIdx.x * 256 + threadIdx.x;
    int row = t / 384;
    int kc = (t - row * 384) * 8;
    int r = row >> 2, gate = row & 3;
    int sel = kc >> 10;
    int k = kc & 1023;
    const float* src = (sel == 0) ? W01 : ((sel == 1) ? U21 : U11);
    const float4* p = reinterpret_cast<const float4*>(src + (size_t)(gate * Hd + r) * Hd + k);
    float4 v0 = p[0], v1 = p[1];
    u16x8 o;
    o[0] = f2bf(v0.x); o[1] = f2bf(v0.y); o[2] = f2bf(v0.z); o[3] = f2bf(v0.w);
    o[4] = f2bf(v1.x); o[5] = f2bf(v1.y); o[6] = f2bf(v1.z); o[7] = f2bf(v1.w);
    *reinterpret_cast<u16x8*>(Ab + (size_t)row * Kc + kc) = o;
}

// ---------------------------------------------------------------------------
// prep_B: B_catT bf16 [4096(n)][3072(k')]  (transpose + per-column z gating)
// ---------------------------------------------------------------------------
__global__ __launch_bounds__(256) void prep_B(const float* __restrict__ hb,
                                              const float* __restrict__ ht,
                                              const float* __restrict__ hh,
                                              const float* __restrict__ z,
                                              const float* __restrict__ zb,
                                              u16* __restrict__ Bb) {
    __shared__ float tile[64][33];
    int n0 = blockIdx.x * 32;
    int kg0 = blockIdx.y * 64;
    int sel = kg0 >> 10;
    int k0 = kg0 & 1023;
    const float* src = (sel == 0) ? hb : ((sel == 1) ? ht : hh);
    int t = threadIdx.x, tx = t & 31, ty = t >> 5;
#pragma unroll
    for (int j = 0; j < 8; ++j) {
        int kk = ty * 8 + j;
        tile[kk][tx] = src[(size_t)(k0 + kk) * Bsz + n0 + tx];
    }
    __syncthreads();
    int kp = t & 31, ny = t >> 5;
#pragma unroll
    for (int j = 0; j < 4; ++j) {
        int nl = ny * 4 + j;
        int n = n0 + nl;
        float s = (sel == 0) ? 1.0f : ((sel == 1) ? z[n] : zb[n]);
        u16x2 o;
        o[0] = f2bf(tile[kp * 2][nl] * s);
        o[1] = f2bf(tile[kp * 2 + 1][nl] * s);
        *reinterpret_cast<u16x2*>(Bb + (size_t)n * Kc + kg0 + kp * 2) = o;
    }
}

// ---------------------------------------------------------------------------
// zrow: f32 row 4096 of f_s -> z_new = step(hard_sigm > 0.5)
// ---------------------------------------------------------------------------
__global__ __launch_bounds__(256) void zrow(const float* __restrict__ hb,
                                            const float* __restrict__ ht,
                                            const float* __restrict__ hh,
                                            const float* __restrict__ z,
                                            const float* __restrict__ zb,
                                            const float* __restrict__ U11,
                                            const float* __restrict__ U21,
                                            const float* __restrict__ W01,
                                            const float* __restrict__ bias,
                                            float* __restrict__ out) {
    __shared__ float wrow0[1024], wrow1[1024], wrow2[1024];
    __shared__ float red[8][32];
    int t = threadIdx.x;
    for (int i = t; i < 1024; i += 256) {
        wrow0[i] = W01[(size_t)4096 * 1024 + i];
        wrow1[i] = U21[(size_t)4096 * 1024 + i];
        wrow2[i] = U11[(size_t)4096 * 1024 + i];
    }
    __syncthreads();
    int col = t & 31, sl = t >> 5;
    int n = blockIdx.x * 32 + col;
    float p0 = 0.f, p1 = 0.f, p2 = 0.f;
    int kend = sl * 128 + 128;
    for (int k = sl * 128; k < kend; ++k) {
        p0 += wrow0[k] * hb[(size_t)k * Bsz + n];
        p1 += wrow1[k] * ht[(size_t)k * Bsz + n];
        p2 += wrow2[k] * hh[(size_t)k * Bsz + n];
    }
    red[sl][col] = p0 + z[n] * p1 + zb[n] * p2;
    __syncthreads();
    if (sl == 0) {
        float s = bias[4096];
#pragma unroll
        for (int q = 0; q < 8; ++q) s += red[q][col];
        float zh = (s + 1.0f) * 0.5f;
        zh = fminf(fmaxf(zh, 0.0f), 1.0f);
        out[(size_t)2 * Hd * Bsz + n] = (zh > 0.5f) ? 1.0f : 0.0f;
    }
}

// ---------------------------------------------------------------------------
// gemm_fused: 256x256 tile, BK=64, 8 waves, 8-phase counted-vmcnt schedule
// (m201 template), XOR-swizzled LDS, fused LSTM epilogue.
// Wave (wm= w>>2, wn= w&3) owns C rows {wm*64 + mh*128}, cols {wn*32 + nh*128}
// so phase (mh,nh) consumption order matches staging order A0,B0,A1,B1.
// ---------------------------------------------------------------------------
__global__ __launch_bounds__(512, 2) void gemm_fused(
    const u16* __restrict__ A, const u16* __restrict__ Bm,
    const float* __restrict__ c_in, const float* __restrict__ h_in,
    const float* __restrict__ z, const float* __restrict__ zb,
    const float* __restrict__ bias, float* __restrict__ out) {
    extern __shared__ __align__(16) u16 smem[];
    u16* const AsB = smem;            // [2][256*64]
    u16* const BsB = smem + 32768;    // [2][256*64]

    const int t = threadIdx.x;
    const int w = t >> 6, l = t & 63;
    const int wm = w >> 2, wn = w & 3;

    const int orig = blockIdx.x;                  // 256 wgs, bijective XCD swizzle
    const int wg = ((orig & 7) << 5) | (orig >> 3);
    const int bm = wg >> 4, bn = wg & 15;

    const int srow = t >> 3;                      // 0..63: row within a stage issue
    const int sgs  = (t & 7) ^ (srow & 7);        // pre-swizzled source granule
    const int fr = l & 15, fq = l >> 4, fkey = l & 7;

    f32x4 acc[8][4];
#pragma unroll
    for (int i = 0; i < 8; ++i)
#pragma unroll
        for (int j = 0; j < 4; ++j) acc[i][j] = (f32x4){0.f, 0.f, 0.f, 0.f};

    const u16* gA = A  + (size_t)(bm * 256 + srow) * Kc + sgs * 8;
    const u16* gB = Bm + (size_t)(bn * 256 + srow) * Kc + sgs * 8;

    auto stageA = [&](int buf, int half, int kt) {
#pragma unroll
        for (int iss = 0; iss < 2; ++iss) {
            const u16* g = gA + (size_t)(half * 128 + iss * 64) * Kc + kt * 64;
            const u16* d = AsB + buf * 16384 + (half * 128 + iss * 64 + (w << 3)) * 64;
            gload16(g, d);
        }
    };
    auto stageB = [&](int buf, int half, int kt) {
#pragma unroll
        for (int iss = 0; iss < 2; ++iss) {
            const u16* g = gB + (size_t)(half * 128 + iss * 64) * Kc + kt * 64;
            const u16* d = BsB + buf * 16384 + (half * 128 + iss * 64 + (w << 3)) * 64;
            gload16(g, d);
        }
    };

    bf16x8 aF[2][4][2];   // [mh][miL][ks]
    bf16x8 bF[2][2];      // [niL][ks] (current nh)

    auto readA = [&](int buf, int mh, int miL, int ks) -> bf16x8 {
        int r = mh * 128 + wm * 64 + miL * 16 + fr;
        int g = ((ks << 2) + fq) ^ fkey;
        return *reinterpret_cast<const bf16x8*>(AsB + buf * 16384 + r * 64 + g * 8);
    };
    auto readB = [&](int buf, int nh, int niL, int ks) -> bf16x8 {
        int r = nh * 128 + wn * 32 + niL * 16 + fr;
        int g = ((ks << 2) + fq) ^ fkey;
        return *reinterpret_cast<const bf16x8*>(BsB + buf * 16384 + r * 64 + g * 8);
    };

    // prologue: stage tile 0 halves in consumption order A0,B0,A1,B1
    stageA(0, 0, 0); stageB(0, 0, 0); stageA(0, 1, 0); stageB(0, 1, 0);
    VMW(4); BAR();

    auto ktile = [&](int tc, auto pfc) {
        constexpr bool pf = decltype(pfc)::value;
        const int cur = tc & 1, nxt = cur ^ 1;
        // ---- phase 0: (mh=0, nh=0) — needs A0,B0
        if constexpr (pf) stageA(nxt, 0, tc + 1);
#pragma unroll
        for (int mi = 0; mi < 4; ++mi) {
            aF[0][mi][0] = readA(cur, 0, mi, 0); aF[0][mi][1] = readA(cur, 0, mi, 1);
        }
#pragma unroll
        for (int ni = 0; ni < 2; ++ni) {
            bF[ni][0] = readB(cur, 0, ni, 0); bF[ni][1] = readB(cur, 0, ni, 1);
        }
        BAR(); LGKM0();
        __builtin_amdgcn_s_setprio(1);
#pragma unroll
        for (int mi = 0; mi < 4; ++mi)
#pragma unroll
            for (int ni = 0; ni < 2; ++ni)
#pragma unroll
                for (int ks = 0; ks < 2; ++ks)
                    acc[mi][ni] = __builtin_amdgcn_mfma_f32_16x16x32_bf16(
                        aF[0][mi][ks], bF[ni][ks], acc[mi][ni], 0, 0, 0);
        __builtin_amdgcn_s_setprio(0);
        if constexpr (pf) { VMW(4); } else { VMW(2); }   // guard A1(cur)
        BAR();
        // ---- phase 1: (mh=1, nh=0) — needs A1 (B0 reused)
        if constexpr (pf) stageB(nxt, 0, tc + 1);
#pragma unroll
        for (int mi = 0; mi < 4; ++mi) {
            aF[1][mi][0] = readA(cur, 1, mi, 0); aF[1][mi][1] = readA(cur, 1, mi, 1);
        }
        BAR(); LGKM0();
        __builtin_amdgcn_s_setprio(1);
#pragma unroll
        for (int mi = 0; mi < 4; ++mi)
#pragma unroll
            for (int ni = 0; ni < 2; ++ni)
#pragma unroll
                for (int ks = 0; ks < 2; ++ks)
                    acc[4 + mi][ni] = __builtin_amdgcn_mfma_f32_16x16x32_bf16(
                        aF[1][mi][ks], bF[ni][ks], acc[4 + mi][ni], 0, 0, 0);
        __builtin_amdgcn_s_setprio(0);
        if constexpr (pf) { VMW(4); } else { VMW(0); }   // guard B1(cur)
        BAR();
        // ---- phase 2: (mh=1, nh=1) — needs B1 (A1 reused)
        if constexpr (pf) stageA(nxt, 1, tc + 1);
#pragma unroll
        for (int ni = 0; ni < 2; ++ni) {
            bF[ni][0] = readB(cur, 1, ni, 0); bF[ni][1] = readB(cur, 1, ni, 1);
        }
        BAR(); LGKM0();
        __builtin_amdgcn_s_setprio(1);
#pragma unroll
        for (int mi = 0; mi < 4; ++mi)
#pragma unroll
            for (int ni = 0; ni < 2; ++ni)
#pragma unroll
                for (int ks = 0; ks < 2; ++ks)
                    acc[4 + mi][2 + ni] = __builtin_amdgcn_mfma_f32_16x16x32_bf16(
                        aF[1][mi][ks], bF[ni][ks], acc[4 + mi][2 + ni], 0, 0, 0);
        __builtin_amdgcn_s_setprio(0);
        BAR();                                            // no vmcnt needed
        // ---- phase 3: (mh=0, nh=1) — A0 still in LDS regs, B1 reused
        if constexpr (pf) stageB(nxt, 1, tc + 1);
        BAR(); LGKM0();
        __builtin_amdgcn_s_setprio(1);
#pragma unroll
        for (int mi = 0; mi < 4; ++mi)
#pragma unroll
            for (int ni = 0; ni < 2; ++ni)
#pragma unroll
                for (int ks = 0; ks < 2; ++ks)
                    acc[mi][2 + ni] = __builtin_amdgcn_mfma_f32_16x16x32_bf16(
                        aF[0][mi][ks], bF[ni][ks], acc[mi][2 + ni], 0, 0, 0);
        __builtin_amdgcn_s_setprio(0);
        if constexpr (pf) { VMW(4); }                     // guard A0,B0(next)
        BAR();
    };

    for (int tc = 0; tc < NT - 1; ++tc) ktile(tc, BoolC<true>{});
    ktile(NT - 1, BoolC<false>{});

    // fused LSTM epilogue: acc[mi][ni] regs = f,i,o,g of unit r, col n
    const int rB = bm * 64;
    const int nB = bn * 256;
    float zc[4], zbv[4];
#pragma unroll
    for (int ni = 0; ni < 4; ++ni) {
        int n = nB + (ni >> 1) * 128 + wn * 32 + (ni & 1) * 16 + fr;
        zc[ni] = z[n]; zbv[ni] = zb[n];
    }
#pragma unroll
    for (int mi = 0; mi < 8; ++mi) {
        const int r = rB + (mi >> 2) * 32 + wm * 16 + (mi & 3) * 4 + fq;
        const float b0 = bias[r], b1 = bias[Hd + r], b2 = bias[2 * Hd + r], b3 = bias[3 * Hd + r];
        const float* crow = c_in + (size_t)r * Bsz;
        const float* hrow = h_in + (size_t)r * Bsz;
        float* hout = out + (size_t)r * Bsz;
        float* cout = out + (size_t)Hd * Bsz + (size_t)r * Bsz;
#pragma unroll
        for (int ni = 0; ni < 4; ++ni) {
            const int n = nB + (ni >> 1) * 128 + wn * 32 + (ni & 1) * 16 + fr;
            f32x4 a = acc[mi][ni];
            float co = crow[n], ho = hrow[n];
            float fg = sigm(a[0] + b0);
            float ig = sigm(a[1] + b1);
            float og = sigm(a[2] + b2);
            float gg = tanhf(a[3] + b3);
            float i_g = ig * gg;
            float nz = 1.0f - zc[ni], nzb = 1.0f - zbv[ni];
            float cn = zc[ni] * i_g + nz * nzb * co + nz * zbv[ni] * (fg * co + i_g);
            float tc2 = tanhf(cn);
            float hn = zc[ni] * og * tc2 + nz * nzb * ho + nz * zbv[ni] * og * tc2;
            hout[n] = hn; cout[n] = cn;
        }
    }
}

extern "C" void kernel_launch(void* const* d_in, const int* in_sizes, int n_in,
                              void* d_out, int out_size, void* d_ws, size_t ws_size,
                              hipStream_t stream) {
    (void)in_sizes; (void)n_in; (void)out_size; (void)ws_size;
    const float* c    = (const float*)d_in[0];
    const float* hb   = (const float*)d_in[1];
    const float* h    = (const float*)d_in[2];
    const float* ht   = (const float*)d_in[3];
    const float* z    = (const float*)d_in[4];
    const float* zb   = (const float*)d_in[5];
    const float* U11  = (const float*)d_in[6];
    const float* U21  = (const float*)d_in[7];
    const float* W01  = (const float*)d_in[8];
    const float* bias = (const float*)d_in[9];
    float* out = (float*)d_out;

    u16* Ab = (u16*)d_ws;                          // 25.2 MB
    u16* Bb = Ab + (size_t)4096 * Kc;              // 25.2 MB

    hipFuncSetAttribute(reinterpret_cast<const void*>(gemm_fused),
                        hipFuncAttributeMaxDynamicSharedMemorySize, 131072);

    prep_A<<<6144, 256, 0, stream>>>(U11, U21, W01, Ab);
    prep_B<<<dim3(128, 48), 256, 0, stream>>>(hb, ht, h, z, zb, Bb);
    zrow<<<128, 256, 0, stream>>>(hb, ht, h, z, zb, U11, U21, W01, bias, out);
    gemm_fused<<<256, 512, 131072, stream>>>(Ab, Bb, c, h, z, zb, bias, out);
}